// Round 8
// baseline (134.221 us; speedup 1.0000x reference)
//
#include <hip/hip_runtime.h>
#include <hip/hip_fp16.h>

#define BB 4
#define NN 8192
#define DD 256
#define HH 8
#define MM 32768   // BB*NN

typedef __attribute__((ext_vector_type(8))) _Float16 half8;
typedef __attribute__((ext_vector_type(4))) _Float16 half4;
typedef __attribute__((ext_vector_type(4))) float f32x4;

#define GLL(src, dst)                                                        \
  __builtin_amdgcn_global_load_lds(                                          \
      (const __attribute__((address_space(1))) void*)(src),                  \
      (__attribute__((address_space(3))) void*)(dst), 16, 0, 0)

// ---------------- K0: W conversion ----------------
// W_qkv [256][1536] fp32 -> Wt [1536][256] fp16 (transposed)
__global__ void __launch_bounds__(256) k_cvt_w(const float* __restrict__ w,
                                               _Float16* __restrict__ wt) {
  int idx = blockIdx.x * 256 + threadIdx.x;  // 0..393215
  int k = idx / 1536, c = idx % 1536;
  wt[(size_t)c * 256 + k] = (_Float16)w[idx];
}

// ---------------- K1: qkv GEMM + norm + rotary + fused dots-partial ----------------
// grid(512): 64 rows, 8 heads, K=256 in 4 panels of 64. 4 waves as (rh, ch):
// wave = rows rh*32..+31 (2 MFMA row-frags) x cols ch*32..+31 of each q|k|v section.
// Each LDS B-read feeds 2 MFMAs (halves LDS read traffic vs 1 row-frag/wave).
// W staged via 3-buffer ring, counted vmcnt(6); epilogue barriers are lgkm-only.
__global__ void __launch_bounds__(256) k_qkv(const float* __restrict__ x,
                                             const _Float16* __restrict__ wt,
                                             const float* __restrict__ pos,
                                             _Float16* __restrict__ q16,
                                             _Float16* __restrict__ part16) {
  __shared__ alignas(16) _Float16 rbuf[3][12288];  // 3 x [192 cols][64 K] swizzled, 72 KB
  __shared__ float2 kpart[2][64];                  // [ch][row] (sum, sumsq)
  __shared__ float2 vpart[2][64];
  const int row0 = blockIdx.x * 64;
  const int t = threadIdx.x;
  const int wv = t >> 6, l = t & 63, lr = l & 15, lg = l >> 4;
  const int rh = wv >> 1, ch = wv & 1;
  const int rowA = row0 + rh * 32 + lr;            // rs=0 row; rs=1 is +16

  // ---- x fragments for BOTH row-frags: coalesced fp32 loads -> fp16 regs ----
  half8 afr[2][8];
#pragma unroll
  for (int rs = 0; rs < 2; ++rs)
#pragma unroll
    for (int c = 0; c < 8; ++c) {    // c = kt*2 + sp
      const float* src = x + (size_t)(rowA + rs * 16) * 256 + c * 32 + lg * 8;
      float4 a = *(const float4*)src;
      float4 b = *(const float4*)(src + 4);
      half8 hv;
      hv[0] = (_Float16)a.x; hv[1] = (_Float16)a.y; hv[2] = (_Float16)a.z; hv[3] = (_Float16)a.w;
      hv[4] = (_Float16)b.x; hv[5] = (_Float16)b.y; hv[6] = (_Float16)b.z; hv[7] = (_Float16)b.w;
      afr[rs][c] = hv;
    }

  // ---- rotary angles: this wave handles dimension ch (0=x, 1=y) only ----
  float sa[2][4], ca[2][4];
#pragma unroll
  for (int rs = 0; rs < 2; ++rs) {
    float p = pos[(size_t)(rowA + rs * 16) * 2 + ch] * 64.0f;
#pragma unroll
    for (int j = 0; j < 4; ++j) {
      float invf = exp2f((float)(lg * 4 + j) * -0.8304820237218405f);  // 10000^(-fi/16)
      __sincosf(p * invf, &sa[rs][j], &ca[rs][j]);
    }
  }

  // ---- W stage for phase p (p = h*4 + kt); data index wraps past 31 ----
  auto stageP = [&](int p) {
    const int pd = p & 31;
    const int hh = pd >> 2, kt = pd & 3;
    char* dst = (char*)&rbuf[p % 3][0];
#pragma unroll
    for (int call = 0; call < 6; ++call) {
      int ob = (call * 4 + wv) * 1024;             // wave-uniform dest base (bytes)
      int o = ob + l * 16;                         // this lane's dest byte
      int c = o >> 7;                              // col 0..191
      int kb = (o & 127) ^ ((c & 7) << 4);         // logical K byte (XOR swizzle)
      int gc = ((c >> 6) << 9) + (hh << 6) + (c & 63);  // global wt row
      const char* src = (const char*)(wt + (size_t)gc * 256 + kt * 64) + kb;
      GLL(src, dst + ob);
    }
  };

  stageP(0); stageP(1);
  asm volatile("s_waitcnt vmcnt(6)" ::: "memory");   // stage(0) complete
  __builtin_amdgcn_s_barrier();
  __builtin_amdgcn_sched_barrier(0);

#pragma unroll 1
  for (int h = 0; h < 8; ++h) {
    f32x4 acc[3][2][2] = {};   // [section s][sub-frag f][row-frag rs]
#pragma unroll
    for (int kt = 0; kt < 4; ++kt) {               // unrolled: afr static index
      const int p = h * 4 + kt;
      stageP(p + 2);                               // 6 GLL, lands 2 phases ahead
      const char* wbp = (const char*)&rbuf[p % 3][0];
#pragma unroll
      for (int sp = 0; sp < 2; ++sp) {
        const int wkb = sp * 64 + lg * 16;
#pragma unroll
        for (int s = 0; s < 3; ++s)
#pragma unroll
          for (int f = 0; f < 2; ++f) {
            int c = s * 64 + ch * 32 + f * 16 + lr;   // block-local col
            half8 bf = *(const half8*)(wbp + c * 128 + (wkb ^ ((c & 7) << 4)));
#pragma unroll
            for (int rs = 0; rs < 2; ++rs)
              acc[s][f][rs] =
                  __builtin_amdgcn_mfma_f32_16x16x32_f16(bf, afr[rs][kt * 2 + sp],
                                                         acc[s][f][rs], 0, 0, 0);
          }
      }
      asm volatile("s_waitcnt vmcnt(6)" ::: "memory");  // counted: newest stage in flight
      __builtin_amdgcn_s_barrier();
      __builtin_amdgcn_sched_barrier(0);
    }
    // (4h+3)%3 == h%3: the just-read buffer is dead until stage(4h+6)
    _Float16* dead = &rbuf[h % 3][0];   // kT: [64 d][88 rows]; vT at +5632 halfs

    // ---- norm partials (this wave's 32 cols of k and v) ----
    float sk[2] = {0.f, 0.f}, sk2[2] = {0.f, 0.f}, sv[2] = {0.f, 0.f}, sv2[2] = {0.f, 0.f};
#pragma unroll
    for (int rs = 0; rs < 2; ++rs)
#pragma unroll
      for (int f = 0; f < 2; ++f)
#pragma unroll
        for (int j = 0; j < 4; ++j) {
          float u = acc[1][f][rs][j]; sk[rs] += u; sk2[rs] += u * u;
          float w = acc[2][f][rs][j]; sv[rs] += w; sv2[rs] += w * w;
        }
#pragma unroll
    for (int rs = 0; rs < 2; ++rs) {
      sk[rs] += __shfl_xor(sk[rs], 16, 64);  sk[rs] += __shfl_xor(sk[rs], 32, 64);
      sk2[rs] += __shfl_xor(sk2[rs], 16, 64); sk2[rs] += __shfl_xor(sk2[rs], 32, 64);
      sv[rs] += __shfl_xor(sv[rs], 16, 64);  sv[rs] += __shfl_xor(sv[rs], 32, 64);
      sv2[rs] += __shfl_xor(sv2[rs], 16, 64); sv2[rs] += __shfl_xor(sv2[rs], 32, 64);
    }
    if (lg == 0) {
#pragma unroll
      for (int rs = 0; rs < 2; ++rs) {
        int r = rh * 32 + rs * 16 + lr;
        kpart[ch][r] = make_float2(sk[rs], sk2[rs]);
        vpart[ch][r] = make_float2(sv[rs], sv2[rs]);
      }
    }
    asm volatile("s_waitcnt lgkmcnt(0)" ::: "memory");   // LDS-only barrier (no vm drain)
    __builtin_amdgcn_s_barrier();
    __builtin_amdgcn_sched_barrier(0);

    float mk[2], ik[2], mv[2], iv[2];
#pragma unroll
    for (int rs = 0; rs < 2; ++rs) {
      int r = rh * 32 + rs * 16 + lr;
      float2 ka = kpart[0][r], kb = kpart[1][r];
      float2 va = vpart[0][r], vb = vpart[1][r];
      mk[rs] = (ka.x + kb.x) * 0.015625f;
      ik[rs] = rsqrtf((ka.y + kb.y) * 0.015625f - mk[rs] * mk[rs] + 1e-5f);
      mv[rs] = (va.x + vb.x) * 0.015625f;
      iv[rs] = rsqrtf((va.y + vb.y) * 0.015625f - mv[rs] * mv[rs] + 1e-5f);
    }

    // ---- q: rotary + store (cols ch*32 + f*16 + lg*4+j of head h) ----
#pragma unroll
    for (int rs = 0; rs < 2; ++rs) {
      size_t qb = (size_t)(rowA + rs * 16) * 512 + h * 64 + ch * 32 + lg * 4;
      half4 o0, o1;
#pragma unroll
      for (int j = 0; j < 4; ++j) {
        float a0 = acc[0][0][rs][j], a1 = acc[0][1][rs][j];
        o0[j] = (_Float16)(a0 * ca[rs][j] - a1 * sa[rs][j]);
        o1[j] = (_Float16)(a1 * ca[rs][j] + a0 * sa[rs][j]);
      }
      *(half4*)(q16 + qb) = o0;
      *(half4*)(q16 + qb + 16) = o1;
    }
    // ---- k: norm + rotary; v: norm -> dead buffer kT[d][row] / vT[e][row] ----
#pragma unroll
    for (int rs = 0; rs < 2; ++rs) {
      int r = rh * 32 + rs * 16 + lr;
#pragma unroll
      for (int j = 0; j < 4; ++j) {
        int d0 = ch * 32 + lg * 4 + j;
        float k0 = (acc[1][0][rs][j] - mk[rs]) * ik[rs];
        float k1 = (acc[1][1][rs][j] - mk[rs]) * ik[rs];
        dead[d0 * 88 + r]        = (_Float16)(k0 * ca[rs][j] - k1 * sa[rs][j]);
        dead[(d0 + 16) * 88 + r] = (_Float16)(k1 * ca[rs][j] + k0 * sa[rs][j]);
        dead[5632 + d0 * 88 + r]        = (_Float16)((acc[2][0][rs][j] - mv[rs]) * iv[rs]);
        dead[5632 + (d0 + 16) * 88 + r] = (_Float16)((acc[2][1][rs][j] - mv[rs]) * iv[rs]);
      }
    }
    asm volatile("s_waitcnt lgkmcnt(0)" ::: "memory");
    __builtin_amdgcn_s_barrier();
    __builtin_amdgcn_sched_barrier(0);

    // ---- dots partial: D[d][e] = sum_rows kT[d][row] vT[e][row], K=64 ----
    f32x4 dacc[4] = {};
#pragma unroll
    for (int ks = 0; ks < 2; ++ks) {
      half8 adf = *(const half8*)(dead + (wv * 16 + lr) * 88 + ks * 32 + lg * 8);
#pragma unroll
      for (int ep = 0; ep < 4; ++ep) {
        half8 bdf = *(const half8*)(dead + 5632 + (ep * 16 + lr) * 88 + ks * 32 + lg * 8);
        dacc[ep] = __builtin_amdgcn_mfma_f32_16x16x32_f16(adf, bdf, dacc[ep], 0, 0, 0);
      }
    }
    asm volatile("s_waitcnt lgkmcnt(0)" ::: "memory");   // dots reads done
    __builtin_amdgcn_s_barrier();                        // before next stage overwrites
    __builtin_amdgcn_sched_barrier(0);

    // partial layout [e][d]: lane holds d = wv*16 + lg*4+{0..3}, e = ep*16+lr
    _Float16* pdst = part16 + ((size_t)blockIdx.x * 8 + h) * 4096;
#pragma unroll
    for (int ep = 0; ep < 4; ++ep) {
      half4 o;
#pragma unroll
      for (int j = 0; j < 4; ++j) o[j] = (_Float16)dacc[ep][j];
      *(half4*)(pdst + (ep * 16 + lr) * 64 + wv * 16 + lg * 4) = o;
    }
  }
}

// ---------------- K2: reduce 512 rowtile partials -> dots fp32 [32 bh][e*64+d] ----
__global__ void __launch_bounds__(256) k_pred(const _Float16* __restrict__ part16,
                                              float* __restrict__ dots) {
  __shared__ float red[4][512];
  const int bh = blockIdx.x >> 3, sl = blockIdx.x & 7;
  const int b = bh >> 3, h = bh & 7;
  const int t = threadIdx.x, wv = t >> 6, l = t & 63;
  float s[8] = {};
  const _Float16* base = part16 + ((size_t)(b * 128) * 8 + h) * 4096 + sl * 512 + l * 8;
#pragma unroll 4
  for (int i = 0; i < 32; ++i) {
    int rt = wv * 32 + i;
    half8 v = *(const half8*)(base + (size_t)rt * 32768);
#pragma unroll
    for (int m = 0; m < 8; ++m) s[m] += (float)v[m];
  }
#pragma unroll
  for (int m = 0; m < 8; ++m) red[wv][l * 8 + m] = s[m];
  __syncthreads();
#pragma unroll
  for (int e = t; e < 512; e += 256) {
    float r = red[0][e] + red[1][e] + red[2][e] + red[3][e];
    dots[(size_t)bh * 4096 + sl * 512 + e] = r;
  }
}

// ---------------- K2b: wdt[b][j][h*64+d] = (1/N) sum_e dotsT[e][d] wout[h*64+e][j]
// grid(32, 4): bid = b*8+h, j-quarter = blockIdx.y*64.
__global__ void __launch_bounds__(256) k_wd(const float* __restrict__ dots,
                                            const float* __restrict__ wout,
                                            _Float16* __restrict__ wdt) {
  __shared__ alignas(16) _Float16 a_lds[4096];    // [64 d][64 e] swizzled, 8 KB
  __shared__ alignas(16) _Float16 b_lds[4096];    // [64 jl][64 e] swizzled, 8 KB
  const int bid = blockIdx.x, b = bid >> 3, hh = bid & 7;
  const int j0 = blockIdx.y * 64;
  const int t = threadIdx.x, wv = t >> 6, l = t & 63, lr = l & 15, lg = l >> 4;

  // A: dots [e][d] fp32 -> a_lds [d][e] fp16 (scaled)
#pragma unroll
  for (int g = 0; g < 4; ++g) {
    int i4 = (g * 256 + t) * 4;  // 0..4095, e = i4>>6, d = i4&63
    f32x4 s = *(const f32x4*)(dots + (size_t)bid * 4096 + i4);
    int e = i4 >> 6, d0 = i4 & 63;
#pragma unroll
    for (int m = 0; m < 4; ++m) {
      int d = d0 + m;
      *(_Float16*)((char*)a_lds + d * 128 + ((e * 2) ^ ((d & 7) << 4))) =
          (_Float16)(s[m] * (1.0f / 8192.0f));
    }
  }
  // B: wout rows hh*64..+63, cols j0..+63, transposed to [jl][e] fp16
#pragma unroll
  for (int g = 0; g < 4; ++g) {
    int i4 = (g * 256 + t) * 4;  // 0..4095: e = i4>>6, jl = i4&63
    int e = i4 >> 6, jl0 = i4 & 63;
    f32x4 u = *(const f32x4*)(wout + (size_t)(hh * 64 + e) * 256 + j0 + jl0);
#pragma unroll
    for (int m = 0; m < 4; ++m) {
      int jl = jl0 + m;
      *(_Float16*)((char*)b_lds + jl * 128 + ((e * 2) ^ ((jl & 7) << 4))) = (_Float16)u[m];
    }
  }
  __syncthreads();

  f32x4 acc[4] = {};
#pragma unroll
  for (int sp = 0; sp < 2; ++sp) {
    int kb = sp * 64 + lg * 16;
    half8 bf;
    {
      int jl = wv * 16 + lr;
      bf = *(const half8*)((const char*)b_lds + jl * 128 + (kb ^ ((jl & 7) << 4)));
    }
#pragma unroll
    for (int ad = 0; ad < 4; ++ad) {
      int d = ad * 16 + lr;
      half8 af = *(const half8*)((const char*)a_lds + d * 128 + (kb ^ ((d & 7) << 4)));
      acc[ad] = __builtin_amdgcn_mfma_f32_16x16x32_f16(af, bf, acc[ad], 0, 0, 0);
    }
  }
  // D[row=d][col=j]: lane holds d = ad*16+lg*4+{0..3}, j = j0 + wv*16 + lr
#pragma unroll
  for (int ad = 0; ad < 4; ++ad) {
    int j = j0 + wv * 16 + lr;
    half4 o;
#pragma unroll
    for (int jj = 0; jj < 4; ++jj) o[jj] = (_Float16)acc[ad][jj];
    *(half4*)(wdt + (size_t)b * 131072 + (size_t)j * 512 + hh * 64 + ad * 16 + lg * 4) = o;
  }
}

// ---------------- K3: out = q16 @ wdt[b] + b_out ----------------
__global__ void __launch_bounds__(256) k_out(const _Float16* __restrict__ q16,
                                             const _Float16* __restrict__ wdt,
                                             const float* __restrict__ bout,
                                             float* __restrict__ out) {
  __shared__ alignas(16) _Float16 qa[2][4096];     // [64 rows][64 K] 8 KB x2
  __shared__ alignas(16) _Float16 wtile[2][16384]; // [256 cols][64 K] 32 KB x2
  const int row0 = blockIdx.x * 64;
  const int b = row0 >> 13;
  const _Float16* wb = wdt + (size_t)b * 131072;
  const int t = threadIdx.x, wv = t >> 6, l = t & 63, lr = l & 15, lg = l >> 4;

  auto stage = [&](int buf, int kt) {
#pragma unroll
    for (int call = 0; call < 2; ++call) {
      int ob = (call * 4 + wv) * 1024;
      int o = ob + l * 16;
      int r = o >> 7;
      int kb = (o & 127) ^ ((r & 7) << 4);
      const char* src = (const char*)(q16 + (size_t)(row0 + r) * 512 + kt * 64) + kb;
      GLL(src, (char*)&qa[buf][0] + ob);
    }
#pragma unroll
    for (int call = 0; call < 8; ++call) {
      int ob = (call * 4 + wv) * 1024;
      int o = ob + l * 16;
      int c = o >> 7;
      int kb = (o & 127) ^ ((c & 7) << 4);
      const char* src = (const char*)(wb + (size_t)c * 512 + kt * 64) + kb;
      GLL(src, (char*)&wtile[buf][0] + ob);
    }
  };

  f32x4 acc[16] = {};
  stage(0, 0);
  __syncthreads();
#pragma unroll 1
  for (int kt = 0; kt < 8; ++kt) {
    int cur = kt & 1;
    if (kt < 7) stage(cur ^ 1, kt + 1);
    const int arow = wv * 16 + lr;
#pragma unroll
    for (int sp = 0; sp < 2; ++sp) {
      int kb = sp * 64 + lg * 16;
      half8 af = *(const half8*)((const char*)&qa[cur][0] + arow * 128 + (kb ^ ((arow & 7) << 4)));
#pragma unroll
      for (int cf = 0; cf < 16; ++cf) {
        int c = cf * 16 + lr;
        half8 bf = *(const half8*)((const char*)&wtile[cur][0] + c * 128 + (kb ^ ((c & 7) << 4)));
        acc[cf] = __builtin_amdgcn_mfma_f32_16x16x32_f16(af, bf, acc[cf], 0, 0, 0);
      }
    }
    __syncthreads();
  }
#pragma unroll
  for (int cf = 0; cf < 16; ++cf) {
    int col = cf * 16 + lr;
    float bo = bout[col];
#pragma unroll
    for (int j = 0; j < 4; ++j) {
      int grow = row0 + wv * 16 + lg * 4 + j;
      out[(size_t)grow * 256 + col] = acc[cf][j] + bo;
    }
  }
}

// ---------------- launch ----------------
extern "C" void kernel_launch(void* const* d_in, const int* in_sizes, int n_in,
                              void* d_out, int out_size, void* d_ws, size_t ws_size,
                              hipStream_t stream) {
  const float* x    = (const float*)d_in[0];
  const float* pos  = (const float*)d_in[1];
  const float* wqkv = (const float*)d_in[2];
  const float* wout = (const float*)d_in[3];
  const float* bout = (const float*)d_in[4];
  float* out = (float*)d_out;
  char* ws = (char*)d_ws;

  _Float16* wt16   = (_Float16*)(ws + 0);          //    786,432 B
  _Float16* q16    = (_Float16*)(ws + 786432);     // 33,554,432 B
  _Float16* part16 = (_Float16*)(ws + 34340864);   // 33,554,432 B
  float*    dots   = (float*)   (ws + 67895296);   //    524,288 B
  _Float16* wdt    = (_Float16*)(ws + 68419584);   //  1,048,576 B (end 69,468,160)

  k_cvt_w<<<1536, 256, 0, stream>>>(wqkv, wt16);
  k_qkv<<<512, 256, 0, stream>>>(x, wt16, pos, q16, part16);
  k_pred<<<256, 256, 0, stream>>>(part16, dots);
  k_wd<<<dim3(32, 4), 256, 0, stream>>>(dots, wout, wdt);
  k_out<<<512, 256, 0, stream>>>(q16, wdt, bout, out);
}

// Round 9
// 112.017 us; speedup vs baseline: 1.1982x; 1.1982x over previous
//
#include <hip/hip_runtime.h>
#include <hip/hip_fp16.h>

#define BB 4
#define NN 8192
#define DD 256
#define HH 8
#define MM 32768   // BB*NN

typedef __attribute__((ext_vector_type(8))) _Float16 half8;
typedef __attribute__((ext_vector_type(4))) _Float16 half4;
typedef __attribute__((ext_vector_type(4))) float f32x4;

#define GLL(src, dst)                                                        \
  __builtin_amdgcn_global_load_lds(                                          \
      (const __attribute__((address_space(1))) void*)(src),                  \
      (__attribute__((address_space(3))) void*)(dst), 16, 0, 0)

// ---------------- K0: W conversion ----------------
// W_qkv [256][1536] fp32 -> Wt [1536][256] fp16 (transposed)
__global__ void __launch_bounds__(256) k_cvt_w(const float* __restrict__ w,
                                               _Float16* __restrict__ wt) {
  int idx = blockIdx.x * 256 + threadIdx.x;  // 0..393215
  int k = idx / 1536, c = idx % 1536;
  wt[(size_t)c * 256 + k] = (_Float16)w[idx];
}

// ---------------- K1: qkv GEMM + norm + rotary + fused dots-partial ----------------
// grid(512): 64 rows, 8 heads, K=256 in 4 panels of 64. 4 waves = (rh, ch):
// rows rh*32..+31 (2 row-frags rs). Cols: ch=0 -> k[0..63] + q[0..31] (x-rotary);
//                                    ch=1 -> v[0..63] + q[32..63] (y-rotary).
// Norm is fully in-wave (2 shfl). 12 B-reads feed 24 MFMA per phase per wave.
// W staged via 3-buffer ring, counted vmcnt(6); epilogue barriers lgkm-only.
__global__ void __launch_bounds__(256) k_qkv(const float* __restrict__ x,
                                             const _Float16* __restrict__ wt,
                                             const float* __restrict__ pos,
                                             _Float16* __restrict__ q16,
                                             _Float16* __restrict__ part16) {
  __shared__ alignas(16) _Float16 rbuf[3][12288];  // 3 x [192 cols][64 K] swizzled, 72 KB
  const int row0 = blockIdx.x * 64;
  const int t = threadIdx.x;
  const int wv = t >> 6, l = t & 63, lr = l & 15, lg = l >> 4;
  const int rh = wv >> 1, ch = wv & 1;
  const int rowA = row0 + rh * 32 + lr;            // rs=0 row; rs=1 is +16

  // block-local B-col base per col-frag (wave-uniform)
  int cbase[6];
#pragma unroll
  for (int cf = 0; cf < 6; ++cf)
    cbase[cf] = (cf < 4) ? ((ch ? 128 : 64) + cf * 16)      // section: k or v
                         : (ch * 32 + (cf - 4) * 16);       // q half

  // ---- x fragments for BOTH row-frags: coalesced fp32 loads -> fp16 regs ----
  half8 afr[2][8];
#pragma unroll
  for (int rs = 0; rs < 2; ++rs)
#pragma unroll
    for (int c = 0; c < 8; ++c) {    // c = kt*2 + sp
      const float* src = x + (size_t)(rowA + rs * 16) * 256 + c * 32 + lg * 8;
      float4 a = *(const float4*)src;
      float4 b = *(const float4*)(src + 4);
      half8 hv;
      hv[0] = (_Float16)a.x; hv[1] = (_Float16)a.y; hv[2] = (_Float16)a.z; hv[3] = (_Float16)a.w;
      hv[4] = (_Float16)b.x; hv[5] = (_Float16)b.y; hv[6] = (_Float16)b.z; hv[7] = (_Float16)b.w;
      afr[rs][c] = hv;
    }

  // ---- rotary angles (once per block): both dims, freq index = lg*4+j ----
  float sx[2][4], cx[2][4], sy[2][4], cy[2][4];
#pragma unroll
  for (int rs = 0; rs < 2; ++rs) {
    float px = pos[(size_t)(rowA + rs * 16) * 2 + 0] * 64.0f;
    float py = pos[(size_t)(rowA + rs * 16) * 2 + 1] * 64.0f;
#pragma unroll
    for (int j = 0; j < 4; ++j) {
      float invf = exp2f((float)(lg * 4 + j) * -0.8304820237218405f);  // 10000^(-fi/16)
      __sincosf(px * invf, &sx[rs][j], &cx[rs][j]);
      __sincosf(py * invf, &sy[rs][j], &cy[rs][j]);
    }
  }

  // ---- W stage for phase p (p = h*4 + kt); data index wraps past 31 ----
  auto stageP = [&](int p) {
    const int pd = p & 31;
    const int hh = pd >> 2, kt = pd & 3;
    char* dst = (char*)&rbuf[p % 3][0];
#pragma unroll
    for (int call = 0; call < 6; ++call) {
      int ob = (call * 4 + wv) * 1024;             // wave-uniform dest base (bytes)
      int o = ob + l * 16;                         // this lane's dest byte
      int c = o >> 7;                              // col 0..191
      int kb = (o & 127) ^ ((c & 7) << 4);         // logical K byte (XOR swizzle)
      int gc = ((c >> 6) << 9) + (hh << 6) + (c & 63);  // global wt row
      const char* src = (const char*)(wt + (size_t)gc * 256 + kt * 64) + kb;
      GLL(src, dst + ob);
    }
  };

  stageP(0); stageP(1);
  asm volatile("s_waitcnt vmcnt(6)" ::: "memory");   // stage(0) complete
  __builtin_amdgcn_s_barrier();

#pragma unroll 1
  for (int h = 0; h < 8; ++h) {
    f32x4 acc[6][2] = {};   // [col-frag cf][row-frag rs]
#pragma unroll
    for (int kt = 0; kt < 4; ++kt) {               // unrolled: afr static index
      const int p = h * 4 + kt;
      stageP(p + 2);                               // 6 GLL, lands 2 phases ahead
      const char* wbp = (const char*)&rbuf[p % 3][0];
#pragma unroll
      for (int sp = 0; sp < 2; ++sp) {
        const int wkb = sp * 64 + lg * 16;
#pragma unroll
        for (int cf = 0; cf < 6; ++cf) {
          int c = cbase[cf] + lr;
          half8 bf = *(const half8*)(wbp + c * 128 + (wkb ^ ((c & 7) << 4)));
#pragma unroll
          for (int rs = 0; rs < 2; ++rs)
            acc[cf][rs] = __builtin_amdgcn_mfma_f32_16x16x32_f16(
                bf, afr[rs][kt * 2 + sp], acc[cf][rs], 0, 0, 0);
        }
      }
      asm volatile("s_waitcnt vmcnt(6)" ::: "memory");  // counted: newest stage in flight
      __builtin_amdgcn_s_barrier();
    }
    // (4h+3)%3 == h%3: the just-read buffer is dead until stage(4h+6)
    _Float16* dead = &rbuf[h % 3][0];   // kT: [64 d][88 rows]; vT at +5632 halfs

    // ---- section norm stats (ch=0: k, ch=1: v) — fully in-wave ----
    float sm[2] = {0.f, 0.f}, s2[2] = {0.f, 0.f};
#pragma unroll
    for (int rs = 0; rs < 2; ++rs) {
#pragma unroll
      for (int cf = 0; cf < 4; ++cf)
#pragma unroll
        for (int j = 0; j < 4; ++j) {
          float u = acc[cf][rs][j];
          sm[rs] += u; s2[rs] += u * u;
        }
      sm[rs] += __shfl_xor(sm[rs], 16, 64);  sm[rs] += __shfl_xor(sm[rs], 32, 64);
      s2[rs] += __shfl_xor(s2[rs], 16, 64);  s2[rs] += __shfl_xor(s2[rs], 32, 64);
    }
    float mn[2], inv[2];
#pragma unroll
    for (int rs = 0; rs < 2; ++rs) {
      mn[rs] = sm[rs] * 0.015625f;
      inv[rs] = rsqrtf(s2[rs] * 0.015625f - mn[rs] * mn[rs] + 1e-5f);
    }

    if (ch == 0) {
      // ---- k: norm + rotary -> dead kT[d][r]; q_lo: x-rotary -> global ----
#pragma unroll
      for (int rs = 0; rs < 2; ++rs) {
        int r = rh * 32 + rs * 16 + lr;
        half4 o0, o1;
#pragma unroll
        for (int j = 0; j < 4; ++j) {
          float k0 = (acc[0][rs][j] - mn[rs]) * inv[rs];
          float k1 = (acc[1][rs][j] - mn[rs]) * inv[rs];
          float k2 = (acc[2][rs][j] - mn[rs]) * inv[rs];
          float k3 = (acc[3][rs][j] - mn[rs]) * inv[rs];
          int d0 = lg * 4 + j;
          dead[d0 * 88 + r]        = (_Float16)(k0 * cx[rs][j] - k1 * sx[rs][j]);
          dead[(d0 + 16) * 88 + r] = (_Float16)(k1 * cx[rs][j] + k0 * sx[rs][j]);
          dead[(d0 + 32) * 88 + r] = (_Float16)(k2 * cy[rs][j] - k3 * sy[rs][j]);
          dead[(d0 + 48) * 88 + r] = (_Float16)(k3 * cy[rs][j] + k2 * sy[rs][j]);
          float a0 = acc[4][rs][j], a1 = acc[5][rs][j];
          o0[j] = (_Float16)(a0 * cx[rs][j] - a1 * sx[rs][j]);
          o1[j] = (_Float16)(a1 * cx[rs][j] + a0 * sx[rs][j]);
        }
        size_t qb = (size_t)(rowA + rs * 16) * 512 + h * 64 + lg * 4;
        *(half4*)(q16 + qb) = o0;
        *(half4*)(q16 + qb + 16) = o1;
      }
    } else {
      // ---- v: norm -> dead vT[e][r]; q_hi: y-rotary -> global ----
#pragma unroll
      for (int rs = 0; rs < 2; ++rs) {
        int r = rh * 32 + rs * 16 + lr;
        half4 o0, o1;
#pragma unroll
        for (int j = 0; j < 4; ++j) {
          int d0 = lg * 4 + j;
          dead[5632 + d0 * 88 + r]        = (_Float16)((acc[0][rs][j] - mn[rs]) * inv[rs]);
          dead[5632 + (d0 + 16) * 88 + r] = (_Float16)((acc[1][rs][j] - mn[rs]) * inv[rs]);
          dead[5632 + (d0 + 32) * 88 + r] = (_Float16)((acc[2][rs][j] - mn[rs]) * inv[rs]);
          dead[5632 + (d0 + 48) * 88 + r] = (_Float16)((acc[3][rs][j] - mn[rs]) * inv[rs]);
          float a0 = acc[4][rs][j], a1 = acc[5][rs][j];
          o0[j] = (_Float16)(a0 * cy[rs][j] - a1 * sy[rs][j]);
          o1[j] = (_Float16)(a1 * cy[rs][j] + a0 * sy[rs][j]);
        }
        size_t qb = (size_t)(rowA + rs * 16) * 512 + h * 64 + 32 + lg * 4;
        *(half4*)(q16 + qb) = o0;
        *(half4*)(q16 + qb + 16) = o1;
      }
    }
    asm volatile("s_waitcnt lgkmcnt(0)" ::: "memory");   // LDS writes done (no vm drain)
    __builtin_amdgcn_s_barrier();

    // ---- dots partial: D[d][e] = sum_rows kT[d][row] vT[e][row], K=64 ----
    f32x4 dacc[4] = {};
#pragma unroll
    for (int ks = 0; ks < 2; ++ks) {
      half8 adf = *(const half8*)(dead + (wv * 16 + lr) * 88 + ks * 32 + lg * 8);
#pragma unroll
      for (int ep = 0; ep < 4; ++ep) {
        half8 bdf = *(const half8*)(dead + 5632 + (ep * 16 + lr) * 88 + ks * 32 + lg * 8);
        dacc[ep] = __builtin_amdgcn_mfma_f32_16x16x32_f16(adf, bdf, dacc[ep], 0, 0, 0);
      }
    }
    asm volatile("s_waitcnt lgkmcnt(0)" ::: "memory");   // dots reads done
    __builtin_amdgcn_s_barrier();                        // before next stage overwrites

    // partial layout [e][d]: lane holds d = wv*16 + lg*4+{0..3}, e = ep*16+lr
    _Float16* pdst = part16 + ((size_t)blockIdx.x * 8 + h) * 4096;
#pragma unroll
    for (int ep = 0; ep < 4; ++ep) {
      half4 o;
#pragma unroll
      for (int j = 0; j < 4; ++j) o[j] = (_Float16)dacc[ep][j];
      *(half4*)(pdst + (ep * 16 + lr) * 64 + wv * 16 + lg * 4) = o;
    }
  }
}

// ---------------- K2: reduce 512 rowtile partials -> dots fp32 [32 bh][e*64+d] ----
__global__ void __launch_bounds__(256) k_pred(const _Float16* __restrict__ part16,
                                              float* __restrict__ dots) {
  __shared__ float red[4][512];
  const int bh = blockIdx.x >> 3, sl = blockIdx.x & 7;
  const int b = bh >> 3, h = bh & 7;
  const int t = threadIdx.x, wv = t >> 6, l = t & 63;
  float s[8] = {};
  const _Float16* base = part16 + ((size_t)(b * 128) * 8 + h) * 4096 + sl * 512 + l * 8;
#pragma unroll 4
  for (int i = 0; i < 32; ++i) {
    int rt = wv * 32 + i;
    half8 v = *(const half8*)(base + (size_t)rt * 32768);
#pragma unroll
    for (int m = 0; m < 8; ++m) s[m] += (float)v[m];
  }
#pragma unroll
  for (int m = 0; m < 8; ++m) red[wv][l * 8 + m] = s[m];
  __syncthreads();
#pragma unroll
  for (int e = t; e < 512; e += 256) {
    float r = red[0][e] + red[1][e] + red[2][e] + red[3][e];
    dots[(size_t)bh * 4096 + sl * 512 + e] = r;
  }
}

// ---------------- K2b: wdt[b][j][h*64+d] = (1/N) sum_e dotsT[e][d] wout[h*64+e][j]
// grid(32, 4): bid = b*8+h, j-quarter = blockIdx.y*64.
__global__ void __launch_bounds__(256) k_wd(const float* __restrict__ dots,
                                            const float* __restrict__ wout,
                                            _Float16* __restrict__ wdt) {
  __shared__ alignas(16) _Float16 a_lds[4096];    // [64 d][64 e] swizzled, 8 KB
  __shared__ alignas(16) _Float16 b_lds[4096];    // [64 jl][64 e] swizzled, 8 KB
  const int bid = blockIdx.x, b = bid >> 3, hh = bid & 7;
  const int j0 = blockIdx.y * 64;
  const int t = threadIdx.x, wv = t >> 6, l = t & 63, lr = l & 15, lg = l >> 4;

  // A: dots [e][d] fp32 -> a_lds [d][e] fp16 (scaled)
#pragma unroll
  for (int g = 0; g < 4; ++g) {
    int i4 = (g * 256 + t) * 4;  // 0..4095, e = i4>>6, d = i4&63
    f32x4 s = *(const f32x4*)(dots + (size_t)bid * 4096 + i4);
    int e = i4 >> 6, d0 = i4 & 63;
#pragma unroll
    for (int m = 0; m < 4; ++m) {
      int d = d0 + m;
      *(_Float16*)((char*)a_lds + d * 128 + ((e * 2) ^ ((d & 7) << 4))) =
          (_Float16)(s[m] * (1.0f / 8192.0f));
    }
  }
  // B: wout rows hh*64..+63, cols j0..+63, transposed to [jl][e] fp16
#pragma unroll
  for (int g = 0; g < 4; ++g) {
    int i4 = (g * 256 + t) * 4;  // 0..4095: e = i4>>6, jl = i4&63
    int e = i4 >> 6, jl0 = i4 & 63;
    f32x4 u = *(const f32x4*)(wout + (size_t)(hh * 64 + e) * 256 + j0 + jl0);
#pragma unroll
    for (int m = 0; m < 4; ++m) {
      int jl = jl0 + m;
      *(_Float16*)((char*)b_lds + jl * 128 + ((e * 2) ^ ((jl & 7) << 4))) = (_Float16)u[m];
    }
  }
  __syncthreads();

  f32x4 acc[4] = {};
#pragma unroll
  for (int sp = 0; sp < 2; ++sp) {
    int kb = sp * 64 + lg * 16;
    half8 bf;
    {
      int jl = wv * 16 + lr;
      bf = *(const half8*)((const char*)b_lds + jl * 128 + (kb ^ ((jl & 7) << 4)));
    }
#pragma unroll
    for (int ad = 0; ad < 4; ++ad) {
      int d = ad * 16 + lr;
      half8 af = *(const half8*)((const char*)a_lds + d * 128 + (kb ^ ((d & 7) << 4)));
      acc[ad] = __builtin_amdgcn_mfma_f32_16x16x32_f16(af, bf, acc[ad], 0, 0, 0);
    }
  }
  // D[row=d][col=j]: lane holds d = ad*16+lg*4+{0..3}, j = j0 + wv*16 + lr
#pragma unroll
  for (int ad = 0; ad < 4; ++ad) {
    int j = j0 + wv * 16 + lr;
    half4 o;
#pragma unroll
    for (int jj = 0; jj < 4; ++jj) o[jj] = (_Float16)acc[ad][jj];
    *(half4*)(wdt + (size_t)b * 131072 + (size_t)j * 512 + hh * 64 + ad * 16 + lg * 4) = o;
  }
}

// ---------------- K3: out = q16 @ wdt[b] + b_out ----------------
__global__ void __launch_bounds__(256) k_out(const _Float16* __restrict__ q16,
                                             const _Float16* __restrict__ wdt,
                                             const float* __restrict__ bout,
                                             float* __restrict__ out) {
  __shared__ alignas(16) _Float16 qa[2][4096];     // [64 rows][64 K] 8 KB x2
  __shared__ alignas(16) _Float16 wtile[2][16384]; // [256 cols][64 K] 32 KB x2
  const int row0 = blockIdx.x * 64;
  const int b = row0 >> 13;
  const _Float16* wb = wdt + (size_t)b * 131072;
  const int t = threadIdx.x, wv = t >> 6, l = t & 63, lr = l & 15, lg = l >> 4;

  auto stage = [&](int buf, int kt) {
#pragma unroll
    for (int call = 0; call < 2; ++call) {
      int ob = (call * 4 + wv) * 1024;
      int o = ob + l * 16;
      int r = o >> 7;
      int kb = (o & 127) ^ ((r & 7) << 4);
      const char* src = (const char*)(q16 + (size_t)(row0 + r) * 512 + kt * 64) + kb;
      GLL(src, (char*)&qa[buf][0] + ob);
    }
#pragma unroll
    for (int call = 0; call < 8; ++call) {
      int ob = (call * 4 + wv) * 1024;
      int o = ob + l * 16;
      int c = o >> 7;
      int kb = (o & 127) ^ ((c & 7) << 4);
      const char* src = (const char*)(wb + (size_t)c * 512 + kt * 64) + kb;
      GLL(src, (char*)&wtile[buf][0] + ob);
    }
  };

  f32x4 acc[16] = {};
  stage(0, 0);
  __syncthreads();
#pragma unroll 1
  for (int kt = 0; kt < 8; ++kt) {
    int cur = kt & 1;
    if (kt < 7) stage(cur ^ 1, kt + 1);
    const int arow = wv * 16 + lr;
#pragma unroll
    for (int sp = 0; sp < 2; ++sp) {
      int kb = sp * 64 + lg * 16;
      half8 af = *(const half8*)((const char*)&qa[cur][0] + arow * 128 + (kb ^ ((arow & 7) << 4)));
#pragma unroll
      for (int cf = 0; cf < 16; ++cf) {
        int c = cf * 16 + lr;
        half8 bf = *(const half8*)((const char*)&wtile[cur][0] + c * 128 + (kb ^ ((c & 7) << 4)));
        acc[cf] = __builtin_amdgcn_mfma_f32_16x16x32_f16(af, bf, acc[cf], 0, 0, 0);
      }
    }
    __syncthreads();
  }
#pragma unroll
  for (int cf = 0; cf < 16; ++cf) {
    int col = cf * 16 + lr;
    float bo = bout[col];
#pragma unroll
    for (int j = 0; j < 4; ++j) {
      int grow = row0 + wv * 16 + lg * 4 + j;
      out[(size_t)grow * 256 + col] = acc[cf][j] + bo;
    }
  }
}

// ---------------- launch ----------------
extern "C" void kernel_launch(void* const* d_in, const int* in_sizes, int n_in,
                              void* d_out, int out_size, void* d_ws, size_t ws_size,
                              hipStream_t stream) {
  const float* x    = (const float*)d_in[0];
  const float* pos  = (const float*)d_in[1];
  const float* wqkv = (const float*)d_in[2];
  const float* wout = (const float*)d_in[3];
  const float* bout = (const float*)d_in[4];
  float* out = (float*)d_out;
  char* ws = (char*)d_ws;

  _Float16* wt16   = (_Float16*)(ws + 0);          //    786,432 B
  _Float16* q16    = (_Float16*)(ws + 786432);     // 33,554,432 B
  _Float16* part16 = (_Float16*)(ws + 34340864);   // 33,554,432 B
  float*    dots   = (float*)   (ws + 67895296);   //    524,288 B
  _Float16* wdt    = (_Float16*)(ws + 68419584);   //  1,048,576 B (end 69,468,160)

  k_cvt_w<<<1536, 256, 0, stream>>>(wqkv, wt16);
  k_qkv<<<512, 256, 0, stream>>>(x, wt16, pos, q16, part16);
  k_pred<<<256, 256, 0, stream>>>(part16, dots);
  k_wd<<<dim3(32, 4), 256, 0, stream>>>(dots, wout, wdt);
  k_out<<<512, 256, 0, stream>>>(q16, wdt, bout, out);
}